// Round 2
// baseline (435.342 us; speedup 1.0000x reference)
//
#include <hip/hip_runtime.h>

#define BB 8
#define CC 3
#define HH 512
#define WW 512
#define KT 5   // kernel taps per dim

// fast tanh: tanh(v) = (e^{2v}-1)/(e^{2v}+1), clamp to avoid inf/inf
__device__ __forceinline__ float fast_tanh(float v) {
    v = fminf(15.0f, fmaxf(-15.0f, v));
    float t = __expf(2.0f * v);
    return __fdividef(t - 1.0f, t + 1.0f);
}

// Each thread: one pool quad — rows {h0,h0+1}, cols {w0,w0+1}, all 3 channels.
// Small tile => low VGPR => 4 waves/EU for latency hiding (R1 was 204 VGPR,
// 2 waves/EU, latency-bound at 11% occupancy).
__global__ __launch_bounds__(256, 4) void FilterNetworkDownsample_kernel(
    const float* __restrict__ x,        // (B, C, H, W)
    const float* __restrict__ kp,       // (B, 25, H, W)
    float* __restrict__ result,         // (B, C, H, W)
    float* __restrict__ down)           // (B, C, H/2, W/2)
{
    const int gid  = blockIdx.x * blockDim.x + threadIdx.x;
    const int wi   = gid & 255;          // W/2 = 256 pooled cols
    const int rest = gid >> 8;
    const int hb   = rest & 255;         // H/2 = 256 row-pairs
    const int b    = rest >> 8;
    const int w0   = wi << 1;
    const int h0   = hb << 1;

    float acc[2][CC][2];
#pragma unroll
    for (int r = 0; r < 2; ++r)
#pragma unroll
        for (int c = 0; c < CC; ++c)
#pragma unroll
            for (int p = 0; p < 2; ++p) acc[r][c][p] = 0.0f;

    const float* xb = x  + (size_t)b * CC * HH * WW;
    const float* kb = kp + (size_t)b * (KT * KT) * HH * WW;

    const bool left_ok  = (w0 >= 2);        // cols w0-2, w0-1 in range
    const bool right_ok = (w0 + 3 < WW);    // cols w0+2, w0+3 in range

    // Loop over the 6 distinct x rows this 2-row output block touches.
#pragma unroll
    for (int l = 0; l < 6; ++l) {
        const int row = h0 - 2 + l;
        const bool rowok = (row >= 0) && (row < HH);

        // xr[c][q] = x[b, c, row, w0-2+q], q in 0..5 (zero outside image)
        float xr[CC][6];
#pragma unroll
        for (int c = 0; c < CC; ++c) {
            const float* xrow = xb + ((size_t)c * HH + (size_t)row) * WW;
            float2 f0, f1, f2;
            if (rowok && left_ok)  f0 = *reinterpret_cast<const float2*>(xrow + w0 - 2);
            else                   f0 = make_float2(0.f, 0.f);
            if (rowok)             f1 = *reinterpret_cast<const float2*>(xrow + w0);
            else                   f1 = make_float2(0.f, 0.f);
            if (rowok && right_ok) f2 = *reinterpret_cast<const float2*>(xrow + w0 + 2);
            else                   f2 = make_float2(0.f, 0.f);
            xr[c][0] = f0.x; xr[c][1] = f0.y;
            xr[c][2] = f1.x; xr[c][3] = f1.y;
            xr[c][4] = f2.x; xr[c][5] = f2.y;
        }

        // This x row feeds output row r=0 as tap i=l, and r=1 as tap i=l-1.
#pragma unroll
        for (int r = 0; r < 2; ++r) {
            const int i = l - r;
            if (i < 0 || i >= KT) continue;
            const int hrow = h0 + r;

            float th[KT][2];
#pragma unroll
            for (int j = 0; j < KT; ++j) {
                const int k = i * KT + j;
                const float2 wv = *reinterpret_cast<const float2*>(
                    kb + ((size_t)k * HH + (size_t)hrow) * WW + w0);
                th[j][0] = fast_tanh(wv.x);
                th[j][1] = fast_tanh(wv.y);
            }

#pragma unroll
            for (int c = 0; c < CC; ++c)
#pragma unroll
                for (int j = 0; j < KT; ++j)
#pragma unroll
                    for (int p = 0; p < 2; ++p)
                        acc[r][c][p] = fmaf(xr[c][p + j], th[j][p], acc[r][c][p]);
        }
    }

    // Write result (coalesced float2 per row/channel)
#pragma unroll
    for (int r = 0; r < 2; ++r)
#pragma unroll
        for (int c = 0; c < CC; ++c) {
            float2 o = make_float2(acc[r][c][0], acc[r][c][1]);
            *reinterpret_cast<float2*>(
                result + ((size_t)(b * CC + c) * HH + (size_t)(h0 + r)) * WW + w0) = o;
        }

    // Write downsample (coalesced float per channel)
#pragma unroll
    for (int c = 0; c < CC; ++c) {
        float d = (acc[0][c][0] + acc[0][c][1] + acc[1][c][0] + acc[1][c][1]) * 0.25f;
        down[((size_t)(b * CC + c) * (HH / 2) + (size_t)hb) * (WW / 2) + wi] = d;
    }
}

extern "C" void kernel_launch(void* const* d_in, const int* in_sizes, int n_in,
                              void* d_out, int out_size, void* d_ws, size_t ws_size,
                              hipStream_t stream) {
    const float* x  = (const float*)d_in[0];
    const float* kp = (const float*)d_in[1];
    float* result = (float*)d_out;                              // B*C*H*W floats
    float* down   = (float*)d_out + (size_t)BB * CC * HH * WW;  // B*C*(H/2)*(W/2)

    const int threads = BB * (HH / 2) * (WW / 2);   // 524288
    const int block = 256;
    const int grid = threads / block;               // 2048
    FilterNetworkDownsample_kernel<<<grid, block, 0, stream>>>(x, kp, result, down);
}

// Round 3
// 353.692 us; speedup vs baseline: 1.2309x; 1.2309x over previous
//
#include <hip/hip_runtime.h>

#define BB 8
#define CC 3
#define HH 512
#define WW 512
#define KT 5
#define HW ((size_t)HH * (size_t)WW)

// fast tanh: (e^{2v}-1)/(e^{2v}+1), clamped
__device__ __forceinline__ float fast_tanh(float v) {
    v = fminf(15.0f, fmaxf(-15.0f, v));
    float t = __expf(2.0f * v);
    return __fdividef(t - 1.0f, t + 1.0f);
}

// async global->LDS, 16B per lane (dest must be linear: uniform base + lane*16)
__device__ __forceinline__ void gload_lds16(const float* g, float* l) {
    __builtin_amdgcn_global_load_lds(
        (const __attribute__((address_space(1))) void*)g,
        (__attribute__((address_space(3))) void*)l, 16, 0, 0);
}

// Block = one (batch, output-row-pair), 256 threads own 2 cols x 2 rows x 3 ch each.
// kp tap-rows double-buffered in LDS via global_load_lds; x rows roll in registers.
__global__ __launch_bounds__(256) void FilterNetworkDownsample_kernel(
    const float* __restrict__ x,        // (B, C, H, W)
    const float* __restrict__ kp,       // (B, 25, H, W)
    float* __restrict__ result,         // (B, C, H, W)
    float* __restrict__ down)           // (B, C, H/2, W/2)
{
    __shared__ float kbuf[2][10][WW];   // [buf][plane q=j*2+r][col] = 40 KB

    const int tid  = threadIdx.x;
    const int wave = tid >> 6;
    const int lane = tid & 63;
    const int blk  = blockIdx.x;
    const int hb   = blk & 255;         // pooled row index
    const int b    = blk >> 8;
    const int h0   = hb << 1;
    const int w0   = tid;               // pooled col (0..255)
    const int c0   = w0 << 1;           // global col (even)

    const float* xb = x  + (size_t)b * CC * HW;
    const float* kb = kp + (size_t)b * (KT * KT) * HW;

    float acc[2][CC][2] = {};
    float xA[CC][6], xB[CC][6], xN[CC][6];

    // ---- stage tap-row i of kp into kbuf[pb]: 10 planes (j=0..4, r=0..1) ----
    // 20 chunks of 1KB; wave w issues chunks 5w..5w+4. Chunk t: plane q=t>>1,
    // half h=t&1, cols [h*256, h*256+256). Lane handles 16B at col h*256+lane*4.
    auto stage = [&](int pb, int i) {
#pragma unroll
        for (int s = 0; s < 5; ++s) {
            const int t  = wave * 5 + s;
            const int q  = t >> 1;
            const int hh = t & 1;
            const float* g = kb
                + ((size_t)(i * KT + (q >> 1)) * HH + (size_t)(h0 + (q & 1))) * WW
                + hh * 256 + lane * 4;
            float* l = &kbuf[pb][q][hh * 256 + lane * 4];
            gload_lds16(g, l);
        }
    };

    // ---- load x row (cols c0-2 .. c0+3, 3 channels), zero-padded ----
    auto load_xrow = [&](int row, float xr[CC][6]) {
        const bool rowok = (row >= 0) && (row < HH);
#pragma unroll
        for (int c = 0; c < CC; ++c) {
            float2 f0 = make_float2(0.f, 0.f), f1 = f0, f2 = f0;
            if (rowok) {
                const float* xrow = xb + ((size_t)c * HH + (size_t)row) * WW;
                if (c0 >= 2)      f0 = *reinterpret_cast<const float2*>(xrow + c0 - 2);
                                  f1 = *reinterpret_cast<const float2*>(xrow + c0);
                if (c0 + 3 < WW)  f2 = *reinterpret_cast<const float2*>(xrow + c0 + 2);
            }
            xr[c][0] = f0.x; xr[c][1] = f0.y;
            xr[c][2] = f1.x; xr[c][3] = f1.y;
            xr[c][4] = f2.x; xr[c][5] = f2.y;
        }
    };

    // prologue: stage tap-row 0, load first two x rows
    stage(0, 0);
    load_xrow(h0 - 2, xA);
    load_xrow(h0 - 1, xB);
    __syncthreads();

    int pb = 0;
#pragma unroll
    for (int i = 0; i < KT; ++i) {
        if (i < KT - 1) {
            stage(pb ^ 1, i + 1);       // async prefetch next tap-row
            load_xrow(h0 + i, xN);      // prefetch next x row (used next iter)
        }

        // compute from kbuf[pb] with x rows xA (out-row 0) / xB (out-row 1)
#pragma unroll
        for (int j = 0; j < KT; ++j) {
#pragma unroll
            for (int r = 0; r < 2; ++r) {
                const int q = j * 2 + r;
                const float2 wv = *reinterpret_cast<const float2*>(&kbuf[pb][q][c0]);
                const float t0 = fast_tanh(wv.x);
                const float t1 = fast_tanh(wv.y);
                const float (*xr)[6] = (r == 0) ? xA : xB;
#pragma unroll
                for (int c = 0; c < CC; ++c) {
                    acc[r][c][0] = fmaf(xr[c][j + 0], t0, acc[r][c][0]);
                    acc[r][c][1] = fmaf(xr[c][j + 1], t1, acc[r][c][1]);
                }
            }
        }

        // rotate x rows (full unroll => pure register renaming)
        if (i < KT - 1) {
#pragma unroll
            for (int c = 0; c < CC; ++c)
#pragma unroll
                for (int qq = 0; qq < 6; ++qq) {
                    xA[c][qq] = xB[c][qq];
                    xB[c][qq] = xN[c][qq];
                }
        }

        __syncthreads();                // drains stage loads; protects buffer reuse
        pb ^= 1;
    }

    // write result (coalesced float2 per row/channel)
#pragma unroll
    for (int r = 0; r < 2; ++r)
#pragma unroll
        for (int c = 0; c < CC; ++c)
            *reinterpret_cast<float2*>(
                result + ((size_t)(b * CC + c) * HH + (size_t)(h0 + r)) * WW + c0)
                = make_float2(acc[r][c][0], acc[r][c][1]);

    // write downsample (coalesced float per channel)
#pragma unroll
    for (int c = 0; c < CC; ++c)
        down[((size_t)(b * CC + c) * (HH / 2) + (size_t)hb) * (WW / 2) + w0]
            = (acc[0][c][0] + acc[0][c][1] + acc[1][c][0] + acc[1][c][1]) * 0.25f;
}

extern "C" void kernel_launch(void* const* d_in, const int* in_sizes, int n_in,
                              void* d_out, int out_size, void* d_ws, size_t ws_size,
                              hipStream_t stream) {
    const float* x  = (const float*)d_in[0];
    const float* kp = (const float*)d_in[1];
    float* result = (float*)d_out;                              // B*C*H*W floats
    float* down   = (float*)d_out + (size_t)BB * CC * HH * WW;  // B*C*(H/2)*(W/2)

    const int grid = BB * (HH / 2);     // 2048 blocks: one per (b, row-pair)
    FilterNetworkDownsample_kernel<<<grid, 256, 0, stream>>>(x, kp, result, down);
}